// Round 26
// baseline (43.172 us; speedup 1.0000x reference)
//
#include <hip/hip_runtime.h>

#define KCODES 512
#define DDIM   64
#define NPIX   1024                      // 32*32 spatial per batch
#define QELEMS (64 * DDIM * NPIX)        // 4194304
#define PXB    64                        // pixels per block
// Pair reorder bound: ref-grid 1.5e-5 (x2<128) + 4-term MFMA err (typ 1.4e-6,
// >9 sigma at 2.5e-5). 4e-5 covers x2 up to 256 too (3e-5 + mfma).
#define FLAG_GAP 4e-5f

typedef float f32x4 __attribute__((ext_vector_type(4)));
typedef short bf16x8 __attribute__((ext_vector_type(8)));
typedef unsigned int u32;
typedef u32 u32x4 __attribute__((ext_vector_type(4)));

// ws layout: [0,2048) = f32 w2f[512]; [4096, 4096+131072) = packed A-frags
//   frag[(cg*4 + t)*64 + lane], t: 0=h0-hi 1=h1-hi 2=h0-lo 3=h1-lo, 16B each.

__device__ __forceinline__ bf16x8 pack_hi(const float* f) {
  u32x4 wds;
#pragma unroll
  for (int p = 0; p < 4; ++p) {
    u32 u0 = __float_as_uint(f[2 * p]);
    u32 u1 = __float_as_uint(f[2 * p + 1]);
    wds[p] = (u0 >> 16) | (u1 & 0xffff0000u);
  }
  return __builtin_bit_cast(bf16x8, wds);
}
__device__ __forceinline__ bf16x8 pack_lo(const float* f) {
  u32x4 wds;
#pragma unroll
  for (int p = 0; p < 4; ++p) {
    float r0 = f[2 * p]     - __uint_as_float(__float_as_uint(f[2 * p])     & 0xffff0000u);
    float r1 = f[2 * p + 1] - __uint_as_float(__float_as_uint(f[2 * p + 1]) & 0xffff0000u);
    wds[p] = (__float_as_uint(r0) >> 16) | (__float_as_uint(r1) & 0xffff0000u);
  }
  return __builtin_bit_cast(bf16x8, wds);
}

// One-time w-side prep: blocks 0..31 pack fragments; block 32 computes w2f.
__global__ void vq_prep(const float* __restrict__ w,
                        float* __restrict__ w2f_g,
                        bf16x8* __restrict__ frag) {
#pragma clang fp contract(off)
  const int blk = blockIdx.x;
  if (blk == 32) {
    int k = threadIdx.x;                 // 512 threads
    if (k < KCODES) {
      float s = 0.0f;
      for (int d = 0; d < DDIM; ++d) {
        float v = w[d * KCODES + k];
        float p = v * v;                 // rounded product
        s = s + p;                       // rounded add, d ascending (numpy)
      }
      w2f_g[k] = s;
    }
    return;
  }
  if (threadIdx.x >= 256) return;
  const int cg   = blk;                  // code-group 0..31
  const int t    = threadIdx.x >> 6;     // term 0..3
  const int lane = threadIdx.x & 63;
  const int code = cg * 16 + (lane & 15);
  const int h    = t & 1;
  float f[8];
#pragma unroll
  for (int j = 0; j < 8; ++j)
    f[j] = w[(h * 32 + (lane >> 4) * 8 + j) * KCODES + code];
  frag[(cg * 4 + t) * 64 + lane] = (t < 2) ? pack_hi(f) : pack_lo(f);
}

// Wave (ch,pgh): code-half ch (256 codes), pixel-half pgh (32 px as 2 MFMA
// pixel-groups sharing each frag load -> 16 MFMA per 4-load burst). 4-term
// split-bf16, scan fully unrolled (R25, compiler software-pipelines), MFMA
// cluster wrapped in s_setprio (T5: waves are barrier-free/phase-diverse in
// the scan). Race-barrier between merge and fixup skm writes. Near-ties
// re-resolved with the BIT-EXACT numpy fp32 emulation (R3/R7-proven).
__global__ __launch_bounds__(256) void vq_kernel(
    const float* __restrict__ x, const float* __restrict__ w,
    const float* __restrict__ w2f_g, const bf16x8* __restrict__ frag,
    float* __restrict__ qout, float* __restrict__ aout) {
#pragma clang fp contract(off)

  __shared__ float  xs[DDIM][PXB + 1];   // [64][65]: row stride 65 ≡ 1 mod 32
  __shared__ float  w2fs[KCODES];
  __shared__ float  hm1[2][PXB], hm2[2][PXB];
  __shared__ int    hi1[2][PXB];
  __shared__ int    skm[PXB];

  const int tid  = threadIdx.x;
  const int lane = tid & 63;
  const int lr   = lane & 15;            // pixel-col / code-row within 16
  const int lg   = lane >> 4;            // group 0..3
  const int wid  = __builtin_amdgcn_readfirstlane(tid >> 6);
  const int ch   = wid & 1;              // code half 0/1
  const int pgh  = wid >> 1;             // pixel half 0/1
  const int b    = blockIdx.x >> 4;
  const int n0   = (blockIdx.x & 15) * PXB;
  const size_t pixbase = (size_t)blockIdx.x * PXB;
  const int px0  = pgh * 32;             // this wave's 32-pixel range

  // ---- stage x tile into LDS (coalesced); load w2f ----
  {
    const float* xp = x + (size_t)b * (DDIM * NPIX) + n0;
#pragma unroll
    for (int dd = 0; dd < 16; ++dd) {
      int d = dd * 4 + wid;
      xs[d][lane] = xp[(size_t)d * NPIX + lane];
    }
  }
  w2fs[tid]       = w2f_g[tid];
  w2fs[tid + 256] = w2f_g[tid + 256];
  __syncthreads();

  // ---- build x (B) fragments: 2 pixel groups, pixel px0+pg*16+lr ----
  bf16x8 bxh[2][2], bxl[2][2];
#pragma unroll
  for (int pg = 0; pg < 2; ++pg) {
#pragma unroll
    for (int h = 0; h < 2; ++h) {
      float f[8];
#pragma unroll
      for (int j = 0; j < 8; ++j)
        f[j] = xs[h * 32 + lg * 8 + j][px0 + pg * 16 + lr];
      bxh[pg][h] = pack_hi(f);
      bxl[pg][h] = pack_lo(f);
    }
  }

  // ---- MFMA scan over this wave's 16 code-groups, fully unrolled ----
  float m1[2] = {3.4e38f, 3.4e38f};
  float m2[2] = {3.4e38f, 3.4e38f};
  int   i1[2] = {0, 0};
#pragma unroll
  for (int i = 0; i < 16; ++i) {
    const int cg = ch * 16 + i;
    const bf16x8* fr = frag + (size_t)cg * 256 + lane;
    bf16x8 awh0 = fr[0];                 // coalesced dwordx4, L2-resident
    bf16x8 awh1 = fr[64];
    bf16x8 awl0 = fr[128];
    bf16x8 awl1 = fr[192];

    __builtin_amdgcn_s_setprio(1);       // favor this wave through MFMA cluster
#pragma unroll
    for (int pg = 0; pg < 2; ++pg) {
      f32x4 acc = {0.f, 0.f, 0.f, 0.f};
      acc = __builtin_amdgcn_mfma_f32_16x16x32_bf16(awh0, bxh[pg][0], acc, 0, 0, 0);
      acc = __builtin_amdgcn_mfma_f32_16x16x32_bf16(awh1, bxh[pg][1], acc, 0, 0, 0);
      acc = __builtin_amdgcn_mfma_f32_16x16x32_bf16(awl0, bxh[pg][0], acc, 0, 0, 0);
      acc = __builtin_amdgcn_mfma_f32_16x16x32_bf16(awl1, bxh[pg][1], acc, 0, 0, 0);
      acc = __builtin_amdgcn_mfma_f32_16x16x32_bf16(awh0, bxl[pg][0], acc, 0, 0, 0);
      acc = __builtin_amdgcn_mfma_f32_16x16x32_bf16(awh1, bxl[pg][1], acc, 0, 0, 0);
      acc = __builtin_amdgcn_mfma_f32_16x16x32_bf16(awl0, bxl[pg][0], acc, 0, 0, 0);
      acc = __builtin_amdgcn_mfma_f32_16x16x32_bf16(awl1, bxl[pg][1], acc, 0, 0, 0);
      const int codebase = cg * 16 + lg * 4;
#pragma unroll
      for (int r = 0; r < 4; ++r) {      // C: row(code)=lg*4+r, col(pixel)=lr
        int code = codebase + r;
        float s = fmaf(-2.0f, acc[r], w2fs[code]);
        float om = m1[pg];               // 5-op top-2 update
        m1[pg] = fminf(om, s);
        m2[pg] = fminf(m2[pg], fmaxf(om, s));
        i1[pg] = (s < om) ? code : i1[pg];
      }
    }
    __builtin_amdgcn_s_setprio(0);
  }

  // ---- cross-lane top-2 merge over the 4 lg groups (per pixel group) ----
#pragma unroll
  for (int pg = 0; pg < 2; ++pg) {
#pragma unroll
    for (int mi = 0; mi < 2; ++mi) {
      int mask = mi ? 32 : 16;
      float pm1 = __shfl_xor(m1[pg], mask);
      float pm2 = __shfl_xor(m2[pg], mask);
      int   pi1 = __shfl_xor(i1[pg], mask);
      if (pm1 < m1[pg]) { m2[pg] = fminf(m1[pg], pm2); m1[pg] = pm1; i1[pg] = pi1; }
      else              { m2[pg] = fminf(m2[pg], pm1); }
    }
    if (lg == 0) {
      int px = px0 + pg * 16 + lr;
      hm1[ch][px] = m1[pg];
      hm2[ch][px] = m2[pg];
      hi1[ch][px] = i1[pg];
    }
  }
  __syncthreads();

  // ---- merge the two code-halves (both waves of the pair compute) ----
  bool flg = false;
  if (lane < 32) {
    const int px = px0 + lane;
    float a1 = hm1[0][px], a2 = hm2[0][px];
    int   ai = hi1[0][px];
    float b1 = hm1[1][px], b2 = hm2[1][px];
    int   bi = hi1[1][px];
    float M1, M2;
    int   I1;
    if (b1 < a1) { M1 = b1; M2 = fminf(a1, b2); I1 = bi; }  // strict <: low half wins ties
    else         { M1 = a1; M2 = fminf(a2, b1); I1 = ai; }
    if (ch == 0) skm[px] = I1;
    flg = (M2 - M1 < FLAG_GAP);
  }
  unsigned long long bal = __ballot(flg);
  unsigned int fmask = (unsigned int)(bal & 0xFFFFFFFFu);

  __syncthreads();   // merge skm-writes complete before any fixup skm-write

  // ---- bit-exact numpy-emulation fixup, round-robin between the 2 waves ----
  {
    int idx = 0;
    while (fmask) {
      const int Lr = __builtin_ctz(fmask);
      fmask &= fmask - 1;
      if ((idx++ & 1) != ch) continue;
      const int L = px0 + Lr;
      // numpy-exact x2 on demand (seq d, mul+add; broadcast LDS reads)
      float x2L = 0.0f;
      for (int d = 0; d < DDIM; ++d) {
        float xv = xs[d][L];
        float p = xv * xv;
        x2L = x2L + p;
      }
      const int k0 = lane * 8;           // lane covers codes [k0, k0+8)
      float dots[8];
#pragma unroll
      for (int c = 0; c < 8; ++c) dots[c] = 0.f;
      for (int d = 0; d < DDIM; d += 4) {       // unroll-4: 8 dwordx4 in flight
        f32x4 wa[4][2];
        float xv[4];
#pragma unroll
        for (int u = 0; u < 4; ++u) {
          const float* wr = w + (size_t)(d + u) * KCODES + k0;
          wa[u][0] = *reinterpret_cast<const f32x4*>(wr);
          wa[u][1] = *reinterpret_cast<const f32x4*>(wr + 4);
          xv[u] = xs[d + u][L];
        }
#pragma unroll
        for (int u = 0; u < 4; ++u) {    // d ascending: numpy order
#pragma unroll
          for (int c = 0; c < 4; ++c) {
            float p = xv[u] * wa[u][0][c];
            dots[c] = dots[c] + p;
          }
#pragma unroll
          for (int c = 0; c < 4; ++c) {
            float p = xv[u] * wa[u][1][c];
            dots[c + 4] = dots[c + 4] + p;
          }
        }
      }
      float bv = 3.4e38f;
      int   bi = 0;
#pragma unroll
      for (int c = 0; c < 8; ++c) {      // ascending c: strict < keeps lowest k
        float t  = x2L - 2.0f * dots[c];
        float s2 = t + w2fs[k0 + c];
        if (s2 < bv) { bv = s2; bi = k0 + c; }
      }
#pragma unroll
      for (int off = 1; off < 64; off <<= 1) {   // lexicographic min all-reduce
        float ov = __shfl_xor(bv, off);
        int   oi = __shfl_xor(bi, off);
        if (ov < bv || (ov == bv && oi < bi)) { bv = ov; bi = oi; }
      }
      if (lane == 0) skm[L] = bi;
    }
  }
  __syncthreads();

  // ---- outputs ----
  if (tid < PXB) aout[pixbase + tid] = (float)skm[tid];

  {
    float* qp = qout + (size_t)b * (DDIM * NPIX) + n0;
#pragma unroll
    for (int i = 0; i < 16; ++i) {
      int d  = (tid >> 6) + i * 4;
      int px = tid & 63;
      qp[(size_t)d * NPIX + px] = w[d * KCODES + skm[px]];
    }
  }
}

extern "C" void kernel_launch(void* const* d_in, const int* in_sizes, int n_in,
                              void* d_out, int out_size, void* d_ws, size_t ws_size,
                              hipStream_t stream) {
  const float* x = (const float*)d_in[0];
  const float* w = (const float*)d_in[1];
  float* qout = (float*)d_out;
  float* aout = (float*)d_out + QELEMS;

  char*   wsb   = (char*)d_ws;
  float*  w2f_g = (float*)wsb;                   // 2 KB
  bf16x8* frag  = (bf16x8*)(wsb + 4096);         // 128 KB

  vq_prep<<<33, 512, 0, stream>>>(w, w2f_g, frag);
  vq_kernel<<<(65536 / PXB), 256, 0, stream>>>(x, w, w2f_g, frag, qout, aout);
}

// Round 27
// 41.519 us; speedup vs baseline: 1.0398x; 1.0398x over previous
//
#include <hip/hip_runtime.h>

#define KCODES 512
#define DDIM   64
#define NPIX   1024                      // 32*32 spatial per batch
#define QELEMS (64 * DDIM * NPIX)        // 4194304
#define PXB    64                        // pixels per block
// Pair reorder bound: ref-grid 1.5e-5 (x2<128) + 4-term MFMA err (typ 1.4e-6,
// >9 sigma at 2.5e-5). 4e-5 covers x2 up to 256 too (3e-5 + mfma).
#define FLAG_GAP 4e-5f

typedef float f32x4 __attribute__((ext_vector_type(4)));
typedef short bf16x8 __attribute__((ext_vector_type(8)));
typedef unsigned int u32;
typedef u32 u32x4 __attribute__((ext_vector_type(4)));

// ws layout: [0,2048) = f32 w2f[512]; [4096, 4096+131072) = packed A-frags
//   frag[(cg*4 + t)*64 + lane], t: 0=h0-hi 1=h1-hi 2=h0-lo 3=h1-lo, 16B each.

__device__ __forceinline__ bf16x8 pack_hi(const float* f) {
  u32x4 wds;
#pragma unroll
  for (int p = 0; p < 4; ++p) {
    u32 u0 = __float_as_uint(f[2 * p]);
    u32 u1 = __float_as_uint(f[2 * p + 1]);
    wds[p] = (u0 >> 16) | (u1 & 0xffff0000u);
  }
  return __builtin_bit_cast(bf16x8, wds);
}
__device__ __forceinline__ bf16x8 pack_lo(const float* f) {
  u32x4 wds;
#pragma unroll
  for (int p = 0; p < 4; ++p) {
    float r0 = f[2 * p]     - __uint_as_float(__float_as_uint(f[2 * p])     & 0xffff0000u);
    float r1 = f[2 * p + 1] - __uint_as_float(__float_as_uint(f[2 * p + 1]) & 0xffff0000u);
    wds[p] = (__float_as_uint(r0) >> 16) | (__float_as_uint(r1) & 0xffff0000u);
  }
  return __builtin_bit_cast(bf16x8, wds);
}

// One-time w-side prep: blocks 0..31 pack fragments; block 32 computes w2f.
__global__ void vq_prep(const float* __restrict__ w,
                        float* __restrict__ w2f_g,
                        bf16x8* __restrict__ frag) {
#pragma clang fp contract(off)
  const int blk = blockIdx.x;
  if (blk == 32) {
    int k = threadIdx.x;                 // 512 threads
    if (k < KCODES) {
      float s = 0.0f;
      for (int d = 0; d < DDIM; ++d) {
        float v = w[d * KCODES + k];
        float p = v * v;                 // rounded product
        s = s + p;                       // rounded add, d ascending (numpy)
      }
      w2f_g[k] = s;
    }
    return;
  }
  if (threadIdx.x >= 256) return;
  const int cg   = blk;                  // code-group 0..31
  const int t    = threadIdx.x >> 6;     // term 0..3
  const int lane = threadIdx.x & 63;
  const int code = cg * 16 + (lane & 15);
  const int h    = t & 1;
  float f[8];
#pragma unroll
  for (int j = 0; j < 8; ++j)
    f[j] = w[(h * 32 + (lane >> 4) * 8 + j) * KCODES + code];
  frag[(cg * 4 + t) * 64 + lane] = (t < 2) ? pack_hi(f) : pack_lo(f);
}

// Wave (ch,pgh): code-half ch (256 codes), pixel-half pgh (32 px as 2 MFMA
// pixel-groups sharing each frag load -> 16 MFMA per 4-load burst). 4-term
// split-bf16. Scan loop FULLY UNROLLED so the scheduler can software-pipeline
// frag loads several iterations deep (grid is fixed at 4 waves/SIMD, so
// VGPR up to 128 is free). Race-barrier between merge and fixup skm writes.
// Near-ties re-resolved with the BIT-EXACT numpy fp32 emulation (R3/R7).
__global__ __launch_bounds__(256) void vq_kernel(
    const float* __restrict__ x, const float* __restrict__ w,
    const float* __restrict__ w2f_g, const bf16x8* __restrict__ frag,
    float* __restrict__ qout, float* __restrict__ aout) {
#pragma clang fp contract(off)

  __shared__ float  xs[DDIM][PXB + 1];   // [64][65]: row stride 65 ≡ 1 mod 32
  __shared__ float  w2fs[KCODES];
  __shared__ float  hm1[2][PXB], hm2[2][PXB];
  __shared__ int    hi1[2][PXB];
  __shared__ int    skm[PXB];

  const int tid  = threadIdx.x;
  const int lane = tid & 63;
  const int lr   = lane & 15;            // pixel-col / code-row within 16
  const int lg   = lane >> 4;            // group 0..3
  const int wid  = __builtin_amdgcn_readfirstlane(tid >> 6);
  const int ch   = wid & 1;              // code half 0/1
  const int pgh  = wid >> 1;             // pixel half 0/1
  const int b    = blockIdx.x >> 4;
  const int n0   = (blockIdx.x & 15) * PXB;
  const size_t pixbase = (size_t)blockIdx.x * PXB;
  const int px0  = pgh * 32;             // this wave's 32-pixel range

  // ---- stage x tile into LDS (coalesced); load w2f ----
  {
    const float* xp = x + (size_t)b * (DDIM * NPIX) + n0;
#pragma unroll
    for (int dd = 0; dd < 16; ++dd) {
      int d = dd * 4 + wid;
      xs[d][lane] = xp[(size_t)d * NPIX + lane];
    }
  }
  w2fs[tid]       = w2f_g[tid];
  w2fs[tid + 256] = w2f_g[tid + 256];
  __syncthreads();

  // ---- build x (B) fragments: 2 pixel groups, pixel px0+pg*16+lr ----
  bf16x8 bxh[2][2], bxl[2][2];
#pragma unroll
  for (int pg = 0; pg < 2; ++pg) {
#pragma unroll
    for (int h = 0; h < 2; ++h) {
      float f[8];
#pragma unroll
      for (int j = 0; j < 8; ++j)
        f[j] = xs[h * 32 + lg * 8 + j][px0 + pg * 16 + lr];
      bxh[pg][h] = pack_hi(f);
      bxl[pg][h] = pack_lo(f);
    }
  }

  // ---- MFMA scan over this wave's 16 code-groups, FULLY UNROLLED ----
  float m1[2] = {3.4e38f, 3.4e38f};
  float m2[2] = {3.4e38f, 3.4e38f};
  int   i1[2] = {0, 0};
#pragma unroll
  for (int i = 0; i < 16; ++i) {
    const int cg = ch * 16 + i;
    const bf16x8* fr = frag + (size_t)cg * 256 + lane;
    bf16x8 awh0 = fr[0];                 // coalesced dwordx4, L2-resident
    bf16x8 awh1 = fr[64];
    bf16x8 awl0 = fr[128];
    bf16x8 awl1 = fr[192];

#pragma unroll
    for (int pg = 0; pg < 2; ++pg) {
      f32x4 acc = {0.f, 0.f, 0.f, 0.f};
      acc = __builtin_amdgcn_mfma_f32_16x16x32_bf16(awh0, bxh[pg][0], acc, 0, 0, 0);
      acc = __builtin_amdgcn_mfma_f32_16x16x32_bf16(awh1, bxh[pg][1], acc, 0, 0, 0);
      acc = __builtin_amdgcn_mfma_f32_16x16x32_bf16(awl0, bxh[pg][0], acc, 0, 0, 0);
      acc = __builtin_amdgcn_mfma_f32_16x16x32_bf16(awl1, bxh[pg][1], acc, 0, 0, 0);
      acc = __builtin_amdgcn_mfma_f32_16x16x32_bf16(awh0, bxl[pg][0], acc, 0, 0, 0);
      acc = __builtin_amdgcn_mfma_f32_16x16x32_bf16(awh1, bxl[pg][1], acc, 0, 0, 0);
      acc = __builtin_amdgcn_mfma_f32_16x16x32_bf16(awl0, bxl[pg][0], acc, 0, 0, 0);
      acc = __builtin_amdgcn_mfma_f32_16x16x32_bf16(awl1, bxl[pg][1], acc, 0, 0, 0);
      const int codebase = cg * 16 + lg * 4;
#pragma unroll
      for (int r = 0; r < 4; ++r) {      // C: row(code)=lg*4+r, col(pixel)=lr
        int code = codebase + r;
        float s = fmaf(-2.0f, acc[r], w2fs[code]);
        float om = m1[pg];               // 5-op top-2 update
        m1[pg] = fminf(om, s);
        m2[pg] = fminf(m2[pg], fmaxf(om, s));
        i1[pg] = (s < om) ? code : i1[pg];
      }
    }
  }

  // ---- cross-lane top-2 merge over the 4 lg groups (per pixel group) ----
#pragma unroll
  for (int pg = 0; pg < 2; ++pg) {
#pragma unroll
    for (int mi = 0; mi < 2; ++mi) {
      int mask = mi ? 32 : 16;
      float pm1 = __shfl_xor(m1[pg], mask);
      float pm2 = __shfl_xor(m2[pg], mask);
      int   pi1 = __shfl_xor(i1[pg], mask);
      if (pm1 < m1[pg]) { m2[pg] = fminf(m1[pg], pm2); m1[pg] = pm1; i1[pg] = pi1; }
      else              { m2[pg] = fminf(m2[pg], pm1); }
    }
    if (lg == 0) {
      int px = px0 + pg * 16 + lr;
      hm1[ch][px] = m1[pg];
      hm2[ch][px] = m2[pg];
      hi1[ch][px] = i1[pg];
    }
  }
  __syncthreads();

  // ---- merge the two code-halves (both waves of the pair compute) ----
  bool flg = false;
  if (lane < 32) {
    const int px = px0 + lane;
    float a1 = hm1[0][px], a2 = hm2[0][px];
    int   ai = hi1[0][px];
    float b1 = hm1[1][px], b2 = hm2[1][px];
    int   bi = hi1[1][px];
    float M1, M2;
    int   I1;
    if (b1 < a1) { M1 = b1; M2 = fminf(a1, b2); I1 = bi; }  // strict <: low half wins ties
    else         { M1 = a1; M2 = fminf(a2, b1); I1 = ai; }
    if (ch == 0) skm[px] = I1;
    flg = (M2 - M1 < FLAG_GAP);
  }
  unsigned long long bal = __ballot(flg);
  unsigned int fmask = (unsigned int)(bal & 0xFFFFFFFFu);

  __syncthreads();   // merge skm-writes complete before any fixup skm-write

  // ---- bit-exact numpy-emulation fixup, round-robin between the 2 waves ----
  {
    int idx = 0;
    while (fmask) {
      const int Lr = __builtin_ctz(fmask);
      fmask &= fmask - 1;
      if ((idx++ & 1) != ch) continue;
      const int L = px0 + Lr;
      // numpy-exact x2 on demand (seq d, mul+add; broadcast LDS reads)
      float x2L = 0.0f;
      for (int d = 0; d < DDIM; ++d) {
        float xv = xs[d][L];
        float p = xv * xv;
        x2L = x2L + p;
      }
      const int k0 = lane * 8;           // lane covers codes [k0, k0+8)
      float dots[8];
#pragma unroll
      for (int c = 0; c < 8; ++c) dots[c] = 0.f;
      for (int d = 0; d < DDIM; d += 4) {       // unroll-4: 8 dwordx4 in flight
        f32x4 wa[4][2];
        float xv[4];
#pragma unroll
        for (int u = 0; u < 4; ++u) {
          const float* wr = w + (size_t)(d + u) * KCODES + k0;
          wa[u][0] = *reinterpret_cast<const f32x4*>(wr);
          wa[u][1] = *reinterpret_cast<const f32x4*>(wr + 4);
          xv[u] = xs[d + u][L];
        }
#pragma unroll
        for (int u = 0; u < 4; ++u) {    // d ascending: numpy order
#pragma unroll
          for (int c = 0; c < 4; ++c) {
            float p = xv[u] * wa[u][0][c];
            dots[c] = dots[c] + p;
          }
#pragma unroll
          for (int c = 0; c < 4; ++c) {
            float p = xv[u] * wa[u][1][c];
            dots[c + 4] = dots[c + 4] + p;
          }
        }
      }
      float bv = 3.4e38f;
      int   bi = 0;
#pragma unroll
      for (int c = 0; c < 8; ++c) {      // ascending c: strict < keeps lowest k
        float t  = x2L - 2.0f * dots[c];
        float s2 = t + w2fs[k0 + c];
        if (s2 < bv) { bv = s2; bi = k0 + c; }
      }
#pragma unroll
      for (int off = 1; off < 64; off <<= 1) {   // lexicographic min all-reduce
        float ov = __shfl_xor(bv, off);
        int   oi = __shfl_xor(bi, off);
        if (ov < bv || (ov == bv && oi < bi)) { bv = ov; bi = oi; }
      }
      if (lane == 0) skm[L] = bi;
    }
  }
  __syncthreads();

  // ---- outputs ----
  if (tid < PXB) aout[pixbase + tid] = (float)skm[tid];

  {
    float* qp = qout + (size_t)b * (DDIM * NPIX) + n0;
#pragma unroll
    for (int i = 0; i < 16; ++i) {
      int d  = (tid >> 6) + i * 4;
      int px = tid & 63;
      qp[(size_t)d * NPIX + px] = w[d * KCODES + skm[px]];
    }
  }
}

extern "C" void kernel_launch(void* const* d_in, const int* in_sizes, int n_in,
                              void* d_out, int out_size, void* d_ws, size_t ws_size,
                              hipStream_t stream) {
  const float* x = (const float*)d_in[0];
  const float* w = (const float*)d_in[1];
  float* qout = (float*)d_out;
  float* aout = (float*)d_out + QELEMS;

  char*   wsb   = (char*)d_ws;
  float*  w2f_g = (float*)wsb;                   // 2 KB
  bf16x8* frag  = (bf16x8*)(wsb + 4096);         // 128 KB

  vq_prep<<<33, 512, 0, stream>>>(w, w2f_g, frag);
  vq_kernel<<<(65536 / PXB), 256, 0, stream>>>(x, w, w2f_g, frag, qout, aout);
}